// Round 3
// baseline (794.348 us; speedup 1.0000x reference)
//
#include <hip/hip_runtime.h>
#include <hip/hip_bf16.h>
#include <stdint.h>

// FGNN: per-pixel mask-selected complex matmul + per-ring mean + combine.
// y = x @ (mask==0 ? W1 : W2)  (complex)  -- computed via delta trick:
//     y = (x*u) @ (W1-W2) + x @ W2   so each image element is read once.
// Ring mean commutes with the GEMM:
//     s[R] = (segment_sum(x*u)[R] @ W1) / totcnt[R]
// so we ring-sum the INPUT, run a tiny fp32 GEMM for s, and fuse the final
// combine out = u ? 0.5*(y+s) : (y-s) into the main GEMM epilogue.
//
// v4: k_gemm widened to 512 threads / 8 waves (wave tile 16px x 128f).
// Per-wave acc drops 128->64 VGPRs -> ~16 waves/CU (2x occupancy) so the
// A-prefetch, B-DMA and epilogue store latency hide under other waves.
// Pipeline per K-window unchanged: B via global_load_lds from pre-padded bt
// image; A reg-staged one window ahead across raw barriers (counted vmcnt).

#define WH 512
#define NPIX (WH * WH)
#define NF 128
#define NRINGS 363
#define SLAB 1664   // max pixels per ring is ~1608 (annulus pi*(2R+1) at R=255)

typedef unsigned short u16;
typedef __attribute__((ext_vector_type(8))) short short8;
typedef __attribute__((ext_vector_type(4))) float floatx4;

__device__ __forceinline__ u16 f2bf(float x) {
    uint32_t u = __float_as_uint(x);
    uint32_t r = (u + 0x7FFFu + ((u >> 16) & 1u)) >> 16;  // RNE
    return (u16)r;
}
__device__ __forceinline__ uint32_t pk(float a, float b) {
    return (uint32_t)f2bf(a) | ((uint32_t)f2bf(b) << 16);
}
__device__ __forceinline__ short8 negbf(short8 v) {
    union { short8 s; uint32_t u[4]; } x;
    x.s = v;
    x.u[0] ^= 0x80008000u; x.u[1] ^= 0x80008000u;
    x.u[2] ^= 0x80008000u; x.u[3] ^= 0x80008000u;
    return x.s;
}
__device__ __forceinline__ floatx4 mfma16(short8 a, short8 b, floatx4 c) {
    return __builtin_amdgcn_mfma_f32_16x16x32_bf16(a, b, c, 0, 0, 0);
}
__device__ __forceinline__ void dma16(const void* gsrc, void* ldst) {
    __builtin_amdgcn_global_load_lds(
        (const __attribute__((address_space(1))) void*)gsrc,
        (__attribute__((address_space(3))) void*)ldst, 16, 0, 0);
}
// exact floor(sqrt(x^2+y^2)) ring id for pixel p
__device__ __forceinline__ int ring_of(int p) {
    int i = p >> 9, j = p & 511;
    int x = i - 256, y = j - 256;
    int r2 = x * x + y * y;
    int R = (int)sqrtf((float)r2);
    while ((R + 1) * (R + 1) <= r2) R++;
    while (R * R > r2) R--;
    return R;
}

// ---------------- K0: build bf16 weights as pre-padded per-kw LDS image ---
// bt u16 layout: [kw][mat][n][kl] with row stride 40 (pad incl.), i.e. the
// exact byte image the GEMM's LDS B region wants per 32-wide K window.
// mats: 0 = W1r-W2r, 1 = W2r, 2 = W1i-W2i, 3 = W2i.
#define BROW 40
__global__ void k_build_bt(const float* __restrict__ w1r, const float* __restrict__ w1i,
                           const float* __restrict__ w2r, const float* __restrict__ w2i,
                           u16* __restrict__ bt) {
    int n = blockIdx.x, k = threadIdx.x;   // grid 128, block 128
    int src = k * NF + n;
    float a1r = w1r[src], a1i = w1i[src], a2r = w2r[src], a2i = w2i[src];
    int kw = k >> 5, kl = k & 31;
    size_t d = (size_t)kw * 20480 + (size_t)n * BROW + kl;
    bt[d + 0 * 5120] = f2bf(a1r - a2r);
    bt[d + 1 * 5120] = f2bf(a2r);
    bt[d + 2 * 5120] = f2bf(a1i - a2i);
    bt[d + 3 * 5120] = f2bf(a2i);
}

// ---------------- K1: bucket pixels by ring -------------------------------
__global__ void k_scatter(const int* __restrict__ mask, int* __restrict__ ctr,
                          int* __restrict__ totcnt, int* __restrict__ list)
{
    int p = blockIdx.x * 256 + threadIdx.x;
    int R = ring_of(p);
    atomicAdd(&totcnt[R], 1);
    if (mask[p] == 0) {
        int slot = atomicAdd(&ctr[R], 1);
        list[R * SLAB + slot] = p;
    }
}

// ---------------- K2: per-ring sums of masked INPUT (float4 gathers) ------
// block = (ring R, chunk of 128 listed pixels). t bit7 = re/im part,
// bits6:5 = pixel sub-slot j, bits4:0 = float4 column. 4 pixels in flight,
// 16 B/lane loads, LDS reduce over j, then 256 scalar atomics per block.
__global__ __launch_bounds__(256) void k_xsum(
    const float* __restrict__ xr, const float* __restrict__ xi,
    const int* __restrict__ ctr, const int* __restrict__ list,
    float* __restrict__ xsum)
{
    const int R = blockIdx.x;
    const int nu = ctr[R];
    const int s0 = blockIdx.y * 128;
    if (s0 >= nu) return;
    const int n = min(128, nu - s0);
    __shared__ int sl[128];
    __shared__ float4 red4[256];
    const int t = threadIdx.x;
    if (t < 128) sl[t] = (t < n) ? list[R * SLAB + s0 + t] : 0;
    __syncthreads();
    const float* src = (t & 128) ? xi : xr;
    const int c4 = t & 31;
    const int j = (t >> 5) & 3;
    float4 acc = {0.0f, 0.0f, 0.0f, 0.0f};
#pragma unroll 4
    for (int k = j; k < n; k += 4) {
        int p = sl[k];
        float4 v = *(const float4*)(src + (size_t)p * NF + c4 * 4);
        acc.x += v.x; acc.y += v.y; acc.z += v.z; acc.w += v.w;
    }
    red4[t] = acc;
    __syncthreads();
    if ((t & 96) == 0) {   // j == 0 lanes: t in {0..31, 128..159}
        float4 a0 = red4[t], a1 = red4[t + 32], a2 = red4[t + 64], a3 = red4[t + 96];
        int base = R * 256 + ((t >> 7) & 1) * 128 + c4 * 4;
        atomicAdd(&xsum[base + 0], a0.x + a1.x + a2.x + a3.x);
        atomicAdd(&xsum[base + 1], a0.y + a1.y + a2.y + a3.y);
        atomicAdd(&xsum[base + 2], a0.z + a1.z + a2.z + a3.z);
        atomicAdd(&xsum[base + 3], a0.w + a1.w + a2.w + a3.w);
    }
}

// ---------------- K3: tiny fp32 complex GEMM -> ring means ----------------
__global__ __launch_bounds__(256) void k_smean(
    const float* __restrict__ xsum, const int* __restrict__ totcnt,
    const float* __restrict__ w1r, const float* __restrict__ w1i,
    float* __restrict__ smean)
{
    const int R = blockIdx.x;
    const int t = threadIdx.x;
    const int f = t & 127, part = t >> 7;   // part: 0=re, 1=im (wave-uniform)
    __shared__ float sh[256];
    sh[t] = xsum[R * 256 + t];
    __syncthreads();
    float acc = 0.0f;
#pragma unroll 4
    for (int k = 0; k < NF; k++) {
        float ar = sh[k], ai = sh[128 + k];
        float br = w1r[k * NF + f], bi = w1i[k * NF + f];
        acc += part ? (ar * bi + ai * br) : (ar * br - ai * bi);
    }
    float c = (float)totcnt[R];
    c = (c < 1.0f) ? 1.0f : c;
    smean[R * 256 + f * 2 + part] = acc / c;
}

// ---------------- K4: masked complex GEMM + fused finalize ----------------
// 512 threads / 8 waves; block tile 128 px x 128 f; wave tile 16 px x 128 f.
// K=128, BK=32. LDS rows padded to 40 ushorts: conflict-free ds_read_b128.
// Pipeline per K-window:
//   [raw barrier] issue B DMA (5/thread) -> wait A(kw) regs (vmcnt(5), B
//   stays in flight) -> cvt+ds_write A -> vmcnt(0) (B landed) -> issue
//   A(kw+1) loads (stay in flight across the RAW barrier) -> lgkmcnt(0) ->
//   barrier -> 64 MFMAs/wave (hides the A prefetch latency).
#define LDS_AR 0
#define LDS_AI 5120
#define LDS_B  10240   // + mat*5120

__global__ __launch_bounds__(512, 2) void k_gemm(
    const float* __restrict__ xr, const float* __restrict__ xi,
    const int* __restrict__ mask, const u16* __restrict__ bt,
    const float* __restrict__ smean, float* __restrict__ out)
{
    __shared__ u16 lds[30720];  // 60 KB
    const int t = threadIdx.x;
    const int pbase = blockIdx.x * 128;
    const int w = t >> 6, lane = t & 63;
    const int quad = lane >> 4, l16 = lane & 15;

    floatx4 accRe[8], accIm[8];
#pragma unroll
    for (int ni = 0; ni < 8; ni++) {
        accRe[ni] = (floatx4)0.0f;
        accIm[ni] = (floatx4)0.0f;
    }

    // per-lane row mask for the A fragment (row is lane-uniform in a frag)
    const bool uu = (mask[pbase + w * 16 + l16] == 0);

    // staging mapping: thread -> (row, quarter of 32-k window)
    const int sr = t >> 2, sh = t & 3;
    const float4* xr4 = (const float4*)(xr + (size_t)(pbase + sr) * NF);
    const float4* xi4 = (const float4*)(xi + (size_t)(pbase + sr) * NF);

    // prologue: issue A loads for kw=0 (4 vmem)
    float4 pr[2], pi[2];
    {
        int qb = sh * 2;
        pr[0] = xr4[qb]; pr[1] = xr4[qb + 1];
        pi[0] = xi4[qb]; pi[1] = xi4[qb + 1];
    }

    for (int kw = 0; kw < 4; kw++) {
        if (kw) {
            __builtin_amdgcn_s_barrier();        // compute(kw-1) done reading LDS
            __builtin_amdgcn_sched_barrier(0);
            asm volatile("" ::: "memory");
        }
        // ---- issue B DMA for this window (5 x 1KB per wave, pre-padded) --
        {
            const char* src = (const char*)bt + (size_t)kw * 40960 + w * 5120 + lane * 16;
            u16* dst = &lds[LDS_B + w * 2560];
#pragma unroll
            for (int c = 0; c < 5; c++)
                dma16(src + c * 1024, dst + c * 512);
        }
        // ---- wait for A(kw) regs only (B DMA may stay outstanding) -------
        asm volatile("s_waitcnt vmcnt(5)" ::: "memory");
        // ---- cvt + write A(kw) to LDS ------------------------------------
        {
            uint4 a;
            a.x = pk(pr[0].x, pr[0].y); a.y = pk(pr[0].z, pr[0].w);
            a.z = pk(pr[1].x, pr[1].y); a.w = pk(pr[1].z, pr[1].w);
            *(uint4*)&lds[LDS_AR + sr * BROW + sh * 8] = a;
            a.x = pk(pi[0].x, pi[0].y); a.y = pk(pi[0].z, pi[0].w);
            a.z = pk(pi[1].x, pi[1].y); a.w = pk(pi[1].z, pi[1].w);
            *(uint4*)&lds[LDS_AI + sr * BROW + sh * 8] = a;
        }
        // ---- B DMA must have landed before anyone passes the barrier -----
        asm volatile("s_waitcnt vmcnt(0)" ::: "memory");
        // ---- issue A(kw+1); stays in flight across the RAW barrier -------
        if (kw < 3) {
            int qb = (kw + 1) * 8 + sh * 2;
            pr[0] = xr4[qb]; pr[1] = xr4[qb + 1];
            pi[0] = xi4[qb]; pi[1] = xi4[qb + 1];
        }
        asm volatile("s_waitcnt lgkmcnt(0)" ::: "memory");  // A ds_writes visible
        __builtin_amdgcn_s_barrier();
        __builtin_amdgcn_sched_barrier(0);
        asm volatile("" ::: "memory");

        // ---- compute ----
        short8 ar, ai, aru, aiu;
        {
            int r = w * 16 + l16;
            ar = *(short8*)&lds[LDS_AR + r * BROW + quad * 8];
            ai = *(short8*)&lds[LDS_AI + r * BROW + quad * 8];
            aru = uu ? ar : (short8)0;
            aiu = uu ? ai : (short8)0;
        }
#pragma unroll
        for (int ni = 0; ni < 8; ni++) {
            int nrow = ni * 16 + l16;
            short8 bDr = *(short8*)&lds[LDS_B + 0 * 5120 + nrow * BROW + quad * 8];
            short8 b2r = *(short8*)&lds[LDS_B + 1 * 5120 + nrow * BROW + quad * 8];
            short8 bDi = *(short8*)&lds[LDS_B + 2 * 5120 + nrow * BROW + quad * 8];
            short8 b2i = *(short8*)&lds[LDS_B + 3 * 5120 + nrow * BROW + quad * 8];
            short8 bDin = negbf(bDi), b2in = negbf(b2i);
            accRe[ni] = mfma16(aru, bDr,  accRe[ni]);
            accRe[ni] = mfma16(ar,  b2r,  accRe[ni]);
            accRe[ni] = mfma16(aiu, bDin, accRe[ni]);
            accRe[ni] = mfma16(ai,  b2in, accRe[ni]);
            accIm[ni] = mfma16(aru, bDi,  accIm[ni]);
            accIm[ni] = mfma16(ar,  b2i,  accIm[ni]);
            accIm[ni] = mfma16(aiu, bDr,  accIm[ni]);
            accIm[ni] = mfma16(ai,  b2r,  accIm[ni]);
        }
    }

    // ---- fused finalize epilogue: per-pixel ring mean combine ----
    int  Rp[4];
    bool up[4];
#pragma unroll
    for (int r = 0; r < 4; r++) {
        int p = pbase + w * 16 + quad * 4 + r;
        Rp[r] = ring_of(p);
        up[r] = (mask[p] == 0);
    }
#pragma unroll
    for (int ni = 0; ni < 8; ni++)
#pragma unroll
        for (int r = 0; r < 4; r++) {
            int p = pbase + w * 16 + quad * 4 + r;
            int f = ni * 16 + l16;
            float2 sv = *(const float2*)(smean + (size_t)Rp[r] * 256 + f * 2);
            float vre = accRe[ni][r];
            float vim = accIm[ni][r];
            float2 o;
            if (up[r]) { o.x = 0.5f * (vre + sv.x); o.y = 0.5f * (vim + sv.y); }
            else       { o.x = vre - sv.x;          o.y = vim - sv.y; }
            *(float2*)(out + (size_t)p * 256 + f * 2) = o;
        }
}

extern "C" void kernel_launch(void* const* d_in, const int* in_sizes, int n_in,
                              void* d_out, int out_size, void* d_ws, size_t ws_size,
                              hipStream_t stream)
{
    const float* xr  = (const float*)d_in[0];  // image_re [512,512,128]
    const float* xi  = (const float*)d_in[1];  // image_im
    const int*   msk = (const int*)d_in[2];    // mask [512,512] int32
    // d_in[3], d_in[4] = output_re/output_im zero inits (unused)
    const float* w1r = (const float*)d_in[5];
    const float* w1i = (const float*)d_in[6];
    const float* w2r = (const float*)d_in[7];
    const float* w2i = (const float*)d_in[8];
    float* out = (float*)d_out;                // [512,512,128,2] fp32

    // ws layout (bytes):
    //   xsum   [363*256] f32 @ 0         (371,712)  ring sums of masked input
    //   smean  [363*256] f32 @ 371,712   (371,712)  [R][f][{re,im}]
    //   ctr    [363]     i32 @ 743,424   (pad to 1,536)
    //   totcnt [363]     i32 @ 744,960   (pad to 1,536)
    //   list   [363*SLAB] i32 @ 746,496  (2,416,128)
    //   bt     [4*20480] u16 @ 3,162,624 (163,840)  pre-padded per-kw image
    char* wsb = (char*)d_ws;
    float* xsum   = (float*)(wsb + 0);
    float* smean  = (float*)(wsb + 371712);
    int*   ctr    = (int*)(wsb + 743424);
    int*   totcnt = (int*)(wsb + 744960);
    int*   list   = (int*)(wsb + 746496);
    u16*   bt     = (u16*)(wsb + 3162624);

    hipMemsetAsync(d_ws, 0, 746496, stream);  // xsum + ctr + totcnt
    k_build_bt<<<dim3(128), dim3(128), 0, stream>>>(w1r, w1i, w2r, w2i, bt);
    k_scatter<<<dim3(NPIX / 256), dim3(256), 0, stream>>>(msk, ctr, totcnt, list);
    k_xsum<<<dim3(NRINGS, 13), dim3(256), 0, stream>>>(xr, xi, ctr, list, xsum);
    k_smean<<<dim3(NRINGS), dim3(256), 0, stream>>>(xsum, totcnt, w1r, w1i, smean);
    k_gemm<<<dim3(NPIX / 128), dim3(512), 0, stream>>>(xr, xi, msk, bt, smean, out);
}

// Round 4
// 775.479 us; speedup vs baseline: 1.0243x; 1.0243x over previous
//
#include <hip/hip_runtime.h>
#include <hip/hip_bf16.h>
#include <stdint.h>

// FGNN: per-pixel mask-selected complex matmul + per-ring mean + combine.
// y = x @ (mask==0 ? W1 : W2)  (complex)  -- computed via delta trick:
//     y = (x*u) @ (W1-W2) + x @ W2   so each image element is read once.
// Ring mean commutes with the GEMM:
//     s[R] = (segment_sum(x*u)[R] @ W1) / totcnt[R]
// so we ring-sum the INPUT, run a tiny fp32 GEMM for s, and fuse the final
// combine out = u ? 0.5*(y+s) : (y-s) into the main GEMM epilogue.
//
// v5: k_gemm back to the v3 4-wave / 256-thread structure (v4's 8-wave
// split doubled LDS B-reads per MFMA and regressed 19 us). k_xsum chunk
// size raised to 256 pixels (halved atomics + list staging per byte).

#define WH 512
#define NPIX (WH * WH)
#define NF 128
#define NRINGS 363
#define SLAB 1664   // max pixels per ring is ~1608 (annulus pi*(2R+1) at R=255)

typedef unsigned short u16;
typedef __attribute__((ext_vector_type(8))) short short8;
typedef __attribute__((ext_vector_type(4))) float floatx4;

__device__ __forceinline__ u16 f2bf(float x) {
    uint32_t u = __float_as_uint(x);
    uint32_t r = (u + 0x7FFFu + ((u >> 16) & 1u)) >> 16;  // RNE
    return (u16)r;
}
__device__ __forceinline__ uint32_t pk(float a, float b) {
    return (uint32_t)f2bf(a) | ((uint32_t)f2bf(b) << 16);
}
__device__ __forceinline__ short8 negbf(short8 v) {
    union { short8 s; uint32_t u[4]; } x;
    x.s = v;
    x.u[0] ^= 0x80008000u; x.u[1] ^= 0x80008000u;
    x.u[2] ^= 0x80008000u; x.u[3] ^= 0x80008000u;
    return x.s;
}
__device__ __forceinline__ floatx4 mfma16(short8 a, short8 b, floatx4 c) {
    return __builtin_amdgcn_mfma_f32_16x16x32_bf16(a, b, c, 0, 0, 0);
}
__device__ __forceinline__ void dma16(const void* gsrc, void* ldst) {
    __builtin_amdgcn_global_load_lds(
        (const __attribute__((address_space(1))) void*)gsrc,
        (__attribute__((address_space(3))) void*)ldst, 16, 0, 0);
}
// exact floor(sqrt(x^2+y^2)) ring id for pixel p
__device__ __forceinline__ int ring_of(int p) {
    int i = p >> 9, j = p & 511;
    int x = i - 256, y = j - 256;
    int r2 = x * x + y * y;
    int R = (int)sqrtf((float)r2);
    while ((R + 1) * (R + 1) <= r2) R++;
    while (R * R > r2) R--;
    return R;
}

// ---------------- K0: build bf16 weights as pre-padded per-kw LDS image ---
// bt u16 layout: [kw][mat][n][kl] with row stride 40 (pad incl.), i.e. the
// exact byte image the GEMM's LDS B region wants per 32-wide K window.
// mats: 0 = W1r-W2r, 1 = W2r, 2 = W1i-W2i, 3 = W2i.
#define BROW 40
__global__ void k_build_bt(const float* __restrict__ w1r, const float* __restrict__ w1i,
                           const float* __restrict__ w2r, const float* __restrict__ w2i,
                           u16* __restrict__ bt) {
    int n = blockIdx.x, k = threadIdx.x;   // grid 128, block 128
    int src = k * NF + n;
    float a1r = w1r[src], a1i = w1i[src], a2r = w2r[src], a2i = w2i[src];
    int kw = k >> 5, kl = k & 31;
    size_t d = (size_t)kw * 20480 + (size_t)n * BROW + kl;
    bt[d + 0 * 5120] = f2bf(a1r - a2r);
    bt[d + 1 * 5120] = f2bf(a2r);
    bt[d + 2 * 5120] = f2bf(a1i - a2i);
    bt[d + 3 * 5120] = f2bf(a2i);
}

// ---------------- K1: bucket pixels by ring -------------------------------
__global__ void k_scatter(const int* __restrict__ mask, int* __restrict__ ctr,
                          int* __restrict__ totcnt, int* __restrict__ list)
{
    int p = blockIdx.x * 256 + threadIdx.x;
    int R = ring_of(p);
    atomicAdd(&totcnt[R], 1);
    if (mask[p] == 0) {
        int slot = atomicAdd(&ctr[R], 1);
        list[R * SLAB + slot] = p;
    }
}

// ---------------- K2: per-ring sums of masked INPUT (float4 gathers) ------
// block = (ring R, chunk of 256 listed pixels). t bit7 = re/im part,
// bits6:5 = pixel sub-slot j, bits4:0 = float4 column. 4 pixels in flight,
// 16 B/lane loads, LDS reduce over j, then 256 scalar atomics per block.
__global__ __launch_bounds__(256) void k_xsum(
    const float* __restrict__ xr, const float* __restrict__ xi,
    const int* __restrict__ ctr, const int* __restrict__ list,
    float* __restrict__ xsum)
{
    const int R = blockIdx.x;
    const int nu = ctr[R];
    const int s0 = blockIdx.y * 256;
    if (s0 >= nu) return;
    const int n = min(256, nu - s0);
    __shared__ int sl[256];
    __shared__ float4 red4[256];
    const int t = threadIdx.x;
    sl[t] = (t < n) ? list[R * SLAB + s0 + t] : 0;
    __syncthreads();
    const float* src = (t & 128) ? xi : xr;
    const int c4 = t & 31;
    const int j = (t >> 5) & 3;
    float4 acc = {0.0f, 0.0f, 0.0f, 0.0f};
#pragma unroll 4
    for (int k = j; k < n; k += 4) {
        int p = sl[k];
        float4 v = *(const float4*)(src + (size_t)p * NF + c4 * 4);
        acc.x += v.x; acc.y += v.y; acc.z += v.z; acc.w += v.w;
    }
    red4[t] = acc;
    __syncthreads();
    if ((t & 96) == 0) {   // j == 0 lanes: t in {0..31, 128..159}
        float4 a0 = red4[t], a1 = red4[t + 32], a2 = red4[t + 64], a3 = red4[t + 96];
        int base = R * 256 + ((t >> 7) & 1) * 128 + c4 * 4;
        atomicAdd(&xsum[base + 0], a0.x + a1.x + a2.x + a3.x);
        atomicAdd(&xsum[base + 1], a0.y + a1.y + a2.y + a3.y);
        atomicAdd(&xsum[base + 2], a0.z + a1.z + a2.z + a3.z);
        atomicAdd(&xsum[base + 3], a0.w + a1.w + a2.w + a3.w);
    }
}

// ---------------- K3: tiny fp32 complex GEMM -> ring means ----------------
__global__ __launch_bounds__(256) void k_smean(
    const float* __restrict__ xsum, const int* __restrict__ totcnt,
    const float* __restrict__ w1r, const float* __restrict__ w1i,
    float* __restrict__ smean)
{
    const int R = blockIdx.x;
    const int t = threadIdx.x;
    const int f = t & 127, part = t >> 7;   // part: 0=re, 1=im (wave-uniform)
    __shared__ float sh[256];
    sh[t] = xsum[R * 256 + t];
    __syncthreads();
    float acc = 0.0f;
#pragma unroll 4
    for (int k = 0; k < NF; k++) {
        float ar = sh[k], ai = sh[128 + k];
        float br = w1r[k * NF + f], bi = w1i[k * NF + f];
        acc += part ? (ar * bi + ai * br) : (ar * br - ai * bi);
    }
    float c = (float)totcnt[R];
    c = (c < 1.0f) ? 1.0f : c;
    smean[R * 256 + f * 2 + part] = acc / c;
}

// ---------------- K4: masked complex GEMM + fused finalize ----------------
// block tile 128 px x 128 f, 4 waves (wave = 32 px x 128 f), K=128, BK=32.
// LDS rows padded to 40 ushorts (80 B): conflict-free ds_read_b128.
// Pipeline per K-window:
//   [raw barrier] issue B DMA -> wait A(kw) regs (vmcnt(10), B stays in
//   flight) -> cvt+ds_write A -> vmcnt(0) (B landed) -> issue A(kw+1) loads
//   (stay in flight across the RAW barrier) -> lgkmcnt(0) -> barrier ->
//   128 MFMAs (hides the A prefetch latency).
#define LDS_AR 0
#define LDS_AI 5120
#define LDS_B  10240   // + mat*5120

__global__ __launch_bounds__(256, 2) void k_gemm(
    const float* __restrict__ xr, const float* __restrict__ xi,
    const int* __restrict__ mask, const u16* __restrict__ bt,
    const float* __restrict__ smean, float* __restrict__ out)
{
    __shared__ u16 lds[30720];  // 60 KB
    const int t = threadIdx.x;
    const int pbase = blockIdx.x * 128;
    const int w = t >> 6, lane = t & 63;
    const int quad = lane >> 4, l16 = lane & 15;

    floatx4 accRe[2][8], accIm[2][8];
#pragma unroll
    for (int mi = 0; mi < 2; mi++)
#pragma unroll
        for (int ni = 0; ni < 8; ni++) {
            accRe[mi][ni] = (floatx4)0.0f;
            accIm[mi][ni] = (floatx4)0.0f;
        }

    // per-lane row masks for the A fragments (row is lane-uniform in a frag)
    bool uu[2];
    uu[0] = (mask[pbase + w * 32 + l16] == 0);
    uu[1] = (mask[pbase + w * 32 + 16 + l16] == 0);

    // staging mapping: thread -> (row, half of 32-k window)
    const int sr = t >> 1, sh = t & 1;
    const float4* xr4 = (const float4*)(xr + (size_t)(pbase + sr) * NF);
    const float4* xi4 = (const float4*)(xi + (size_t)(pbase + sr) * NF);

    // prologue: issue A loads for kw=0
    float4 pr[4], pi[4];
    {
        int qb = sh * 4;
        pr[0] = xr4[qb]; pr[1] = xr4[qb + 1]; pr[2] = xr4[qb + 2]; pr[3] = xr4[qb + 3];
        pi[0] = xi4[qb]; pi[1] = xi4[qb + 1]; pi[2] = xi4[qb + 2]; pi[3] = xi4[qb + 3];
    }

    for (int kw = 0; kw < 4; kw++) {
        if (kw) {
            __builtin_amdgcn_s_barrier();        // compute(kw-1) done reading LDS
            __builtin_amdgcn_sched_barrier(0);
            asm volatile("" ::: "memory");
        }
        // ---- issue B DMA for this window (10 x 1KB per wave, pre-padded) --
        {
            const char* src = (const char*)bt + (size_t)kw * 40960 + w * 10240 + lane * 16;
            u16* dst = &lds[LDS_B + w * 5120];
#pragma unroll
            for (int c = 0; c < 10; c++)
                dma16(src + c * 1024, dst + c * 512);
        }
        // ---- wait for A(kw) regs only (B DMA may stay outstanding) -------
        asm volatile("s_waitcnt vmcnt(10)" ::: "memory");
        // ---- cvt + write A(kw) to LDS ------------------------------------
        {
            uint4 a, b;
            a.x = pk(pr[0].x, pr[0].y); a.y = pk(pr[0].z, pr[0].w);
            a.z = pk(pr[1].x, pr[1].y); a.w = pk(pr[1].z, pr[1].w);
            b.x = pk(pr[2].x, pr[2].y); b.y = pk(pr[2].z, pr[2].w);
            b.z = pk(pr[3].x, pr[3].y); b.w = pk(pr[3].z, pr[3].w);
            *(uint4*)&lds[LDS_AR + sr * BROW + sh * 16]     = a;
            *(uint4*)&lds[LDS_AR + sr * BROW + sh * 16 + 8] = b;
            a.x = pk(pi[0].x, pi[0].y); a.y = pk(pi[0].z, pi[0].w);
            a.z = pk(pi[1].x, pi[1].y); a.w = pk(pi[1].z, pi[1].w);
            b.x = pk(pi[2].x, pi[2].y); b.y = pk(pi[2].z, pi[2].w);
            b.z = pk(pi[3].x, pi[3].y); b.w = pk(pi[3].z, pi[3].w);
            *(uint4*)&lds[LDS_AI + sr * BROW + sh * 16]     = a;
            *(uint4*)&lds[LDS_AI + sr * BROW + sh * 16 + 8] = b;
        }
        // ---- B DMA must have landed before anyone passes the barrier -----
        asm volatile("s_waitcnt vmcnt(0)" ::: "memory");
        // ---- issue A(kw+1); stays in flight across the RAW barrier -------
        if (kw < 3) {
            int qb = (kw + 1) * 8 + sh * 4;
            pr[0] = xr4[qb]; pr[1] = xr4[qb + 1]; pr[2] = xr4[qb + 2]; pr[3] = xr4[qb + 3];
            pi[0] = xi4[qb]; pi[1] = xi4[qb + 1]; pi[2] = xi4[qb + 2]; pi[3] = xi4[qb + 3];
        }
        asm volatile("s_waitcnt lgkmcnt(0)" ::: "memory");  // A ds_writes visible
        __builtin_amdgcn_s_barrier();
        __builtin_amdgcn_sched_barrier(0);
        asm volatile("" ::: "memory");

        // ---- compute ----
        short8 ar[2], ai[2], aru[2], aiu[2];
#pragma unroll
        for (int mi = 0; mi < 2; mi++) {
            int r = w * 32 + mi * 16 + l16;
            ar[mi] = *(short8*)&lds[LDS_AR + r * BROW + quad * 8];
            ai[mi] = *(short8*)&lds[LDS_AI + r * BROW + quad * 8];
            aru[mi] = uu[mi] ? ar[mi] : (short8)0;
            aiu[mi] = uu[mi] ? ai[mi] : (short8)0;
        }
#pragma unroll
        for (int ni = 0; ni < 8; ni++) {
            int nrow = ni * 16 + l16;
            short8 bDr = *(short8*)&lds[LDS_B + 0 * 5120 + nrow * BROW + quad * 8];
            short8 b2r = *(short8*)&lds[LDS_B + 1 * 5120 + nrow * BROW + quad * 8];
            short8 bDi = *(short8*)&lds[LDS_B + 2 * 5120 + nrow * BROW + quad * 8];
            short8 b2i = *(short8*)&lds[LDS_B + 3 * 5120 + nrow * BROW + quad * 8];
            short8 bDin = negbf(bDi), b2in = negbf(b2i);
#pragma unroll
            for (int mi = 0; mi < 2; mi++) {
                accRe[mi][ni] = mfma16(aru[mi], bDr,  accRe[mi][ni]);
                accRe[mi][ni] = mfma16(ar[mi],  b2r,  accRe[mi][ni]);
                accRe[mi][ni] = mfma16(aiu[mi], bDin, accRe[mi][ni]);
                accRe[mi][ni] = mfma16(ai[mi],  b2in, accRe[mi][ni]);
                accIm[mi][ni] = mfma16(aru[mi], bDi,  accIm[mi][ni]);
                accIm[mi][ni] = mfma16(ar[mi],  b2i,  accIm[mi][ni]);
                accIm[mi][ni] = mfma16(aiu[mi], bDr,  accIm[mi][ni]);
                accIm[mi][ni] = mfma16(ai[mi],  b2r,  accIm[mi][ni]);
            }
        }
    }

    // ---- fused finalize epilogue: per-pixel ring mean combine ----
    int  Rp[2][4];
    bool up[2][4];
#pragma unroll
    for (int mi = 0; mi < 2; mi++)
#pragma unroll
        for (int r = 0; r < 4; r++) {
            int p = pbase + w * 32 + mi * 16 + quad * 4 + r;
            Rp[mi][r] = ring_of(p);
            up[mi][r] = (mask[p] == 0);
        }
#pragma unroll
    for (int mi = 0; mi < 2; mi++)
#pragma unroll
        for (int ni = 0; ni < 8; ni++)
#pragma unroll
            for (int r = 0; r < 4; r++) {
                int p = pbase + w * 32 + mi * 16 + quad * 4 + r;
                int f = ni * 16 + l16;
                float2 sv = *(const float2*)(smean + (size_t)Rp[mi][r] * 256 + f * 2);
                float vre = accRe[mi][ni][r];
                float vim = accIm[mi][ni][r];
                float2 o;
                if (up[mi][r]) { o.x = 0.5f * (vre + sv.x); o.y = 0.5f * (vim + sv.y); }
                else           { o.x = vre - sv.x;          o.y = vim - sv.y; }
                *(float2*)(out + (size_t)p * 256 + f * 2) = o;
            }
}

extern "C" void kernel_launch(void* const* d_in, const int* in_sizes, int n_in,
                              void* d_out, int out_size, void* d_ws, size_t ws_size,
                              hipStream_t stream)
{
    const float* xr  = (const float*)d_in[0];  // image_re [512,512,128]
    const float* xi  = (const float*)d_in[1];  // image_im
    const int*   msk = (const int*)d_in[2];    // mask [512,512] int32
    // d_in[3], d_in[4] = output_re/output_im zero inits (unused)
    const float* w1r = (const float*)d_in[5];
    const float* w1i = (const float*)d_in[6];
    const float* w2r = (const float*)d_in[7];
    const float* w2i = (const float*)d_in[8];
    float* out = (float*)d_out;                // [512,512,128,2] fp32

    // ws layout (bytes):
    //   xsum   [363*256] f32 @ 0         (371,712)  ring sums of masked input
    //   smean  [363*256] f32 @ 371,712   (371,712)  [R][f][{re,im}]
    //   ctr    [363]     i32 @ 743,424   (pad to 1,536)
    //   totcnt [363]     i32 @ 744,960   (pad to 1,536)
    //   list   [363*SLAB] i32 @ 746,496  (2,416,128)
    //   bt     [4*20480] u16 @ 3,162,624 (163,840)  pre-padded per-kw image
    char* wsb = (char*)d_ws;
    float* xsum   = (float*)(wsb + 0);
    float* smean  = (float*)(wsb + 371712);
    int*   ctr    = (int*)(wsb + 743424);
    int*   totcnt = (int*)(wsb + 744960);
    int*   list   = (int*)(wsb + 746496);
    u16*   bt     = (u16*)(wsb + 3162624);

    hipMemsetAsync(d_ws, 0, 746496, stream);  // xsum + ctr + totcnt
    k_build_bt<<<dim3(128), dim3(128), 0, stream>>>(w1r, w1i, w2r, w2i, bt);
    k_scatter<<<dim3(NPIX / 256), dim3(256), 0, stream>>>(msk, ctr, totcnt, list);
    k_xsum<<<dim3(NRINGS, 7), dim3(256), 0, stream>>>(xr, xi, ctr, list, xsum);
    k_smean<<<dim3(NRINGS), dim3(256), 0, stream>>>(xsum, totcnt, w1r, w1i, smean);
    k_gemm<<<dim3(NPIX / 128), dim3(256), 0, stream>>>(xr, xi, msk, bt, smean, out);
}